// Round 13
// baseline (5134.446 us; speedup 1.0000x reference)
//
#include <hip/hip_runtime.h>

#define ZV 147456   // 96*96*16
#define NP 2000
#define CC 128

typedef __attribute__((ext_vector_type(8))) __bf16 bf16x8;
typedef __attribute__((ext_vector_type(4))) float f32x4;

__device__ __forceinline__ int zof(int h, int w, int l) { return (h * 96 + w) * 16 + l; }

// ---------------- NN search (both directions) ----------------
__global__ void nn_kernel(const int* __restrict__ inds_img, const int* __restrict__ inds_pts,
                          int* __restrict__ nn_img, int* __restrict__ nn_pts) {
    int b = blockIdx.x;                 // 0..3999
    int q = (b < NP) ? b : b - NP;
    const int* qi = (b < NP) ? inds_pts : inds_img;
    const int* ki = (b < NP) ? inds_img : inds_pts;
    int qh = qi[q * 4 + 1], qw = qi[q * 4 + 2], ql = qi[q * 4 + 3];
    unsigned long long best = ~0ull;
    for (int k = threadIdx.x; k < NP; k += 64) {
        int dh = qh - ki[k * 4 + 1];
        int dw = qw - ki[k * 4 + 2];
        int dl = ql - ki[k * 4 + 3];
        unsigned long long d2 = (unsigned long long)(dh * dh + dw * dw + dl * dl);
        unsigned long long pack = (d2 << 32) | (unsigned)k;
        best = (pack < best) ? pack : best;
    }
    #pragma unroll
    for (int off = 32; off; off >>= 1) {
        unsigned long long o = __shfl_down(best, off, 64);
        best = (o < best) ? o : best;
    }
    if (threadIdx.x == 0) {
        int idx = (int)(best & 0xffffffffu);
        long long d2 = (long long)(best >> 32);
        int* dst = (b < NP) ? nn_img : nn_pts;
        // val < 13.3  <=>  d2 < 176.89  <=> d2 <= 176 (d2 integer)
        dst[q] = (d2 <= 176) ? idx : -1;
    }
}

// ---------------- gather + linear + elementwise (fused_img / fused_pts values) ----------------
__global__ void fused_kernel(const float* __restrict__ img, const float* __restrict__ pts,
                             const float* __restrict__ lin_w, const float* __restrict__ lin_b,
                             const int* __restrict__ inds_img, const int* __restrict__ inds_pts,
                             const int* __restrict__ nn_img, const int* __restrict__ nn_pts,
                             float* __restrict__ fusedImg, float* __restrict__ fusedPts) {
    __shared__ float f[CC];
    int b = blockIdx.x;   // 0..3999
    int t = threadIdx.x;  // 128
    int p, zsrc, zdst;
    const float* src;
    const float* selsrc;
    float* outp;
    if (b < NP) {
        p = b;
        int idx = nn_img[p]; if (idx < 0) idx += NP;     // jnp negative-index wrap
        const int* gr = inds_img + idx * 4;
        zsrc = zof(gr[1], gr[2], gr[3]);
        const int* pr = inds_pts + p * 4;
        zdst = zof(pr[1], pr[2], pr[3]);
        src = img; selsrc = pts; outp = fusedImg;
    } else {
        p = b - NP;
        int idx = nn_pts[p]; if (idx < 0) idx += NP;
        const int* gr = inds_pts + idx * 4;
        zsrc = zof(gr[1], gr[2], gr[3]);
        const int* pr = inds_img + p * 4;
        zdst = zof(pr[1], pr[2], pr[3]);
        src = pts; selsrc = img; outp = fusedPts;
    }
    f[t] = src[(size_t)t * ZV + zsrc];
    __syncthreads();
    float acc = lin_b[t];
    #pragma unroll 8
    for (int ci = 0; ci < CC; ci++) acc += f[ci] * lin_w[t * CC + ci];
    acc = fmaxf(acc, 0.f) * selsrc[(size_t)t * ZV + zdst];
    outp[p * CC + t] = acc;
}

// ---------------- weight transposes ----------------
// w1t[tap][i][o]  (tap=a*9+b*3+c, i=0..511, o=0..255)
__global__ void tr_w1(const float* __restrict__ w1, float* __restrict__ w1t) {
    int idx = blockIdx.x * 256 + threadIdx.x;   // 512*256 threads
    int o = idx & 255, i = idx >> 8;
    const float* s = w1 + ((size_t)o * 512 + i) * 27;
    #pragma unroll
    for (int tap = 0; tap < 27; tap++) w1t[((size_t)tap * 512 + i) * 256 + o] = s[tap];
}
// w2 split-precision bf16: w2h/w2l [tap][co][ci]
__global__ void tr_w2b(const float* __restrict__ w2,
                       __bf16* __restrict__ w2h, __bf16* __restrict__ w2l) {
    int idx = blockIdx.x * 256 + threadIdx.x;   // 128 blocks * 256 = 32768 = co*ci
    int ci = idx & 255, co = idx >> 8;
    const float* s = w2 + ((size_t)co * 256 + ci) * 27;
    #pragma unroll
    for (int tap = 0; tap < 27; tap++) {
        float v = s[tap];
        __bf16 hb = (__bf16)v;
        float lo = v - (float)hb;
        w2h[((size_t)tap * 128 + co) * 256 + ci] = hb;
        w2l[((size_t)tap * 128 + co) * 256 + ci] = (__bf16)lo;
    }
}

// ---------------- conv1: sparse scatter-GEMM, atomics into y1t[z][co] ----------------
__global__ __launch_bounds__(256) void conv1_kernel(
        const float* __restrict__ img, const float* __restrict__ pts,
        const float* __restrict__ fusedImg, const float* __restrict__ fusedPts,
        const int* __restrict__ inds_img, const int* __restrict__ inds_pts,
        const float* __restrict__ w1t, float* __restrict__ y1t) {
    __shared__ float VA[128][8];
    __shared__ float VB[128][8];
    __shared__ int sh[8], sw[8], sl[8];
    int wg = blockIdx.x;        // 0..499
    int s = wg / 250;           // 0: img coords (blocks 0 & 3), 1: pts coords (blocks 1 & 2)
    int chunk = wg % 250;
    int t = threadIdx.x;        // 256 = co
    const int* coords = s ? inds_pts : inds_img;
    int blA = s ? 1 : 0;
    int blB = s ? 2 : 3;
    const float* dense = s ? pts : img;
    const float* fused = s ? fusedImg : fusedPts;
    if (t < 8) {
        const int* r = coords + (chunk * 8 + t) * 4;
        sh[t] = r[1]; sw[t] = r[2]; sl[t] = r[3];
    }
    __syncthreads();
    for (int e = t; e < 1024; e += 256) {
        int ci = e >> 3, j = e & 7;
        int z = zof(sh[j], sw[j], sl[j]);
        VA[ci][j] = dense[(size_t)ci * ZV + z];
        VB[ci][j] = fused[(chunk * 8 + j) * 128 + ci];
    }
    __syncthreads();
    int co = t;
    for (int tap = 0; tap < 27; tap++) {
        int a = tap / 9, bq = (tap / 3) % 3, c = tap % 3;
        float acc[8] = {0, 0, 0, 0, 0, 0, 0, 0};
        const float* wA = w1t + ((size_t)tap * 512 + blA * 128) * 256 + co;
        const float* wB = w1t + ((size_t)tap * 512 + blB * 128) * 256 + co;
        #pragma unroll 4
        for (int ci = 0; ci < 128; ci++) {
            float a0 = wA[ci * 256];
            float b0 = wB[ci * 256];
            #pragma unroll
            for (int j = 0; j < 8; j++) acc[j] += a0 * VA[ci][j] + b0 * VB[ci][j];
        }
        #pragma unroll
        for (int j = 0; j < 8; j++) {
            int h2 = sh[j] + 1 - a, w2 = sw[j] + 1 - bq, l2 = sl[j] + 1 - c;
            if ((unsigned)h2 < 96u && (unsigned)w2 < 96u && (unsigned)l2 < 16u) {
                atomicAdd(&y1t[(size_t)zof(h2, w2, l2) * 256 + co], acc[j]);
            }
        }
    }
}

// ---------------- BN1 stats over y1t[z][co] ----------------
__global__ void stats1_kernel(const float* __restrict__ y1t, double* __restrict__ dsum,
                              double* __restrict__ dsq) {
    int t = threadIdx.x;            // co
    size_t z0 = (size_t)blockIdx.x * 256;   // 576 blocks
    double s = 0, q = 0;
    for (int r = 0; r < 256; r++) {
        float v = y1t[(z0 + r) * 256 + t];
        s += v;
        q += (double)v * v;
    }
    atomicAdd(&dsum[t], s);
    atomicAdd(&dsq[t], q);
}

__global__ void fin1_kernel(const double* dsum, const double* dsq, const float* g,
                            const float* b, float* a1, float* b1c) {
    int c = threadIdx.x;  // 256
    double mean = dsum[c] / (double)ZV;
    double var = dsq[c] / (double)ZV - mean * mean;
    float a = g[c] * (float)(1.0 / sqrt(var + 1e-3));
    a1[c] = a;
    b1c[c] = b[c] - (float)mean * a;
}

// ---------------- conv2: implicit-GEMM MFMA, bf16 split precision ----------------
// block tile: 2h x 8w x 8l = 128 voxels x 128 co; halo 4x10x10 = 400 pos (3.1x amp)
// -> LDS 51.2 KB -> 3 blocks/CU -> 3 waves/SIMD (was 540 pos / 69 KB / 2 waves).
// 4 waves, each 64vox x 64co = 4x4 frags; K = 27 taps x 256 ci (chunk 32).
// x staged as bf16 hi/lo with XOR swizzle (16B-group ^= pidx&7); tap loop register
// double-buffered (even/odd sets, static indices).
__global__ __launch_bounds__(256, 3) void conv2_kernel(
        const float* __restrict__ y1t,
        const __bf16* __restrict__ w2h, const __bf16* __restrict__ w2l,
        const float* __restrict__ a1, const float* __restrict__ b1c,
        float* __restrict__ y2) {
    __shared__ __align__(16) __bf16 xh[400 * 32];
    __shared__ __align__(16) __bf16 xl[400 * 32];
    int bid = blockIdx.x;
    int wg = (bid & 7) * 144 + (bid >> 3);   // XCD swizzle (1152 = 8*144, bijective)
    int lh = wg & 1;
    int wt = (wg >> 1) % 12;
    int h0 = (wg / 24) * 2;
    int w0 = wt * 8;
    int l0 = lh * 8;
    int t = threadIdx.x;
    int lane = t & 63, wid = t >> 6;
    int wm = wid >> 1, wn = wid & 1;
    int r = lane & 15, kg = lane >> 4;
    int rhi = r >> 3, rlo = r & 7;

    f32x4 acc[4][4];
    #pragma unroll
    for (int i = 0; i < 4; i++)
        #pragma unroll
        for (int j = 0; j < 4; j++) acc[i][j] = (f32x4){0.f, 0.f, 0.f, 0.f};

    for (int ci0 = 0; ci0 < 256; ci0 += 32) {
        __syncthreads();    // protect previous chunk's reads
        for (int pp = t; pp < 400; pp += 256) {
            int lp = pp % 10;
            int wp = (pp / 10) % 10;
            int hp = pp / 100;
            int h2 = h0 + hp - 1, w2c = w0 + wp - 1, l2 = l0 + lp - 1;
            bool ok = ((unsigned)h2 < 96u) && ((unsigned)w2c < 96u) && ((unsigned)l2 < 16u);
            const float* src = y1t + ((size_t)zof(ok ? h2 : 0, ok ? w2c : 0, ok ? l2 : 0) * 256 + ci0);
            #pragma unroll
            for (int g4 = 0; g4 < 4; g4++) {
                float e[8];
                if (ok) {
                    float4 v0 = *(const float4*)(src + g4 * 8);
                    float4 v1 = *(const float4*)(src + g4 * 8 + 4);
                    e[0] = v0.x; e[1] = v0.y; e[2] = v0.z; e[3] = v0.w;
                    e[4] = v1.x; e[5] = v1.y; e[6] = v1.z; e[7] = v1.w;
                } else {
                    #pragma unroll
                    for (int q = 0; q < 8; q++) e[q] = 0.f;
                }
                bf16x8 hv, lv;
                #pragma unroll
                for (int q = 0; q < 8; q++) {
                    int ci = ci0 + g4 * 8 + q;
                    float x = ok ? fmaxf(a1[ci] * e[q] + b1c[ci], 0.f) : 0.f;
                    __bf16 xb = (__bf16)x;
                    hv[q] = xb;
                    lv[q] = (__bf16)(x - (float)xb);
                }
                int gs = (pp * 4 + g4) ^ (pp & 7);
                *(bf16x8*)(xh + (gs << 3)) = hv;
                *(bf16x8*)(xl + (gs << 3)) = lv;
            }
        }
        __syncthreads();

        // even/odd register frag sets -- all indices compile-time (rule: no runtime
        // indexing of ext_vector arrays).
        bf16x8 eAh[4], eAl[4], eBh[4], eBl[4];
        bf16x8 oAh[4], oAl[4], oBh[4], oBl[4];

        // A position: (hp = wm+ta, wp = mf*2+rhi+tb, lp = rlo+tc)
        #define LOADTAP(TP, Ah_, Al_, Bh_, Bl_) do {                                   \
            int ta_ = (TP) / 9, tb_ = ((TP) / 3) % 3, tc_ = (TP) % 3;                  \
            int pbase_ = (wm + ta_) * 100 + (rhi + tb_) * 10 + rlo + tc_;              \
            _Pragma("unroll")                                                          \
            for (int mf_ = 0; mf_ < 4; mf_++) {                                        \
                int pidx_ = pbase_ + mf_ * 20;                                         \
                int gs_ = (pidx_ * 4 + kg) ^ (pidx_ & 7);                              \
                Ah_[mf_] = *(const bf16x8*)(xh + (gs_ << 3));                          \
                Al_[mf_] = *(const bf16x8*)(xl + (gs_ << 3));                          \
            }                                                                          \
            size_t bbase_ = ((size_t)((TP) * 128 + wn * 64 + r)) * 256 + ci0 + kg * 8; \
            _Pragma("unroll")                                                          \
            for (int j_ = 0; j_ < 4; j_++) {                                           \
                Bh_[j_] = *(const bf16x8*)(w2h + bbase_ + j_ * 4096);                  \
                Bl_[j_] = *(const bf16x8*)(w2l + bbase_ + j_ * 4096);                  \
            }                                                                          \
        } while (0)

        // term-major MFMA order: same-acc updates are 16 MFMAs apart (no dep stall)
        #define MFMACLUSTER(Ah_, Al_, Bh_, Bl_) do {                                   \
            _Pragma("unroll")                                                          \
            for (int mf_ = 0; mf_ < 4; mf_++)                                          \
                _Pragma("unroll")                                                      \
                for (int j_ = 0; j_ < 4; j_++)                                         \
                    acc[mf_][j_] = __builtin_amdgcn_mfma_f32_16x16x32_bf16(            \
                        Ah_[mf_], Bh_[j_], acc[mf_][j_], 0, 0, 0);                     \
            _Pragma("unroll")                                                          \
            for (int mf_ = 0; mf_ < 4; mf_++)                                          \
                _Pragma("unroll")                                                      \
                for (int j_ = 0; j_ < 4; j_++)                                         \
                    acc[mf_][j_] = __builtin_amdgcn_mfma_f32_16x16x32_bf16(            \
                        Ah_[mf_], Bl_[j_], acc[mf_][j_], 0, 0, 0);                     \
            _Pragma("unroll")                                                          \
            for (int mf_ = 0; mf_ < 4; mf_++)                                          \
                _Pragma("unroll")                                                      \
                for (int j_ = 0; j_ < 4; j_++)                                         \
                    acc[mf_][j_] = __builtin_amdgcn_mfma_f32_16x16x32_bf16(            \
                        Al_[mf_], Bh_[j_], acc[mf_][j_], 0, 0, 0);                     \
        } while (0)

        LOADTAP(0, eAh, eAl, eBh, eBl);
        #pragma unroll 1
        for (int tap = 0; tap < 27; tap += 2) {
            if (tap + 1 < 27) LOADTAP(tap + 1, oAh, oAl, oBh, oBl);
            MFMACLUSTER(eAh, eAl, eBh, eBl);
            if (tap + 1 < 27) {
                if (tap + 2 < 27) LOADTAP(tap + 2, eAh, eAl, eBh, eBl);
                MFMACLUSTER(oAh, oAl, oBh, oBl);
            }
        }
        #undef LOADTAP
        #undef MFMACLUSTER
    }
    // epilogue: D col = lane&15 (co), row = kg*4 + j -> voxel (w = mf*2 + (kg>>1), l = (kg&1)*4 + j)
    #pragma unroll
    for (int mf = 0; mf < 4; mf++)
        #pragma unroll
        for (int j = 0; j < 4; j++) {
            int co = wn * 64 + j * 16 + r;
            int z = zof(h0 + wm, w0 + mf * 2 + (kg >> 1), l0 + (kg & 1) * 4);
            *(f32x4*)(y2 + (size_t)co * ZV + z) = acc[mf][j];
        }
}

// ---------------- BN2 stats over y2[co][z] ----------------
__global__ void stats2_kernel(const float* __restrict__ y2, double* __restrict__ dsum,
                              double* __restrict__ dsq) {
    __shared__ double sd[256];
    int t = threadIdx.x;
    int co = blockIdx.x >> 2, qu = blockIdx.x & 3;   // 512 blocks
    const float* pp = y2 + (size_t)co * ZV + qu * (ZV / 4);
    double s = 0, q = 0;
    for (int i = t; i < ZV / 4; i += 256) {
        float v = pp[i];
        s += v;
        q += (double)v * v;
    }
    sd[t] = s; __syncthreads();
    for (int o = 128; o; o >>= 1) { if (t < o) sd[t] += sd[t + o]; __syncthreads(); }
    if (t == 0) atomicAdd(&dsum[co], sd[0]);
    __syncthreads();
    sd[t] = q; __syncthreads();
    for (int o = 128; o; o >>= 1) { if (t < o) sd[t] += sd[t + o]; __syncthreads(); }
    if (t == 0) atomicAdd(&dsq[co], sd[0]);
}

__global__ void fin2_kernel(const double* dsum, const double* dsq, const float* g,
                            const float* b, float* a2, float* b2c) {
    int c = threadIdx.x;  // 128
    double mean = dsum[c] / (double)ZV;
    double var = dsq[c] / (double)ZV - mean * mean;
    float a = g[c] * (float)(1.0 / sqrt(var + 1e-3));
    a2[c] = a;
    b2c[c] = b[c] - (float)mean * a;
}

__global__ void final_kernel(float* __restrict__ y2, const float* __restrict__ a2,
                             const float* __restrict__ b2c) {
    int i4 = blockIdx.x * 256 + threadIdx.x;   // 4,718,592 float4s -> 18432 blocks
    size_t i = (size_t)i4 * 4;
    int co = (int)(i / ZV);
    float a = a2[co], bb = b2c[co];
    float4 v = *(float4*)(y2 + i);
    v.x = fmaxf(a * v.x + bb, 0.f);
    v.y = fmaxf(a * v.y + bb, 0.f);
    v.z = fmaxf(a * v.z + bb, 0.f);
    v.w = fmaxf(a * v.w + bb, 0.f);
    *(float4*)(y2 + i) = v;
}

extern "C" void kernel_launch(void* const* d_in, const int* in_sizes, int n_in,
                              void* d_out, int out_size, void* d_ws, size_t ws_size,
                              hipStream_t stream) {
    const float* img = (const float*)d_in[0];
    const float* pts = (const float*)d_in[1];
    const float* w1  = (const float*)d_in[2];
    const float* g1  = (const float*)d_in[3];
    const float* b1  = (const float*)d_in[4];
    const float* w2  = (const float*)d_in[5];
    const float* g2  = (const float*)d_in[6];
    const float* b2  = (const float*)d_in[7];
    const float* lw  = (const float*)d_in[8];
    const float* lbv = (const float*)d_in[9];
    const int* iimg  = (const int*)d_in[10];
    const int* ipts  = (const int*)d_in[11];
    float* out = (float*)d_out;

    char* p = (char*)d_ws;
    auto carve = [&](size_t bytes) {
        char* r = p;
        p += (bytes + 255) & ~(size_t)255;
        return r;
    };
    float* y1t      = (float*)carve((size_t)ZV * 256 * 4);       // 151 MB
    float* w1t      = (float*)carve((size_t)27 * 512 * 256 * 4); // 14.2 MB
    __bf16* w2h     = (__bf16*)carve((size_t)27 * 128 * 256 * 2); // 1.77 MB
    __bf16* w2l     = (__bf16*)carve((size_t)27 * 128 * 256 * 2); // 1.77 MB
    float* fusedImg = (float*)carve((size_t)NP * 128 * 4);
    float* fusedPts = (float*)carve((size_t)NP * 128 * 4);
    int*   nnImg    = (int*)carve(NP * 4);
    int*   nnPts    = (int*)carve(NP * 4);
    double* dsum1   = (double*)carve(256 * 8);
    double* dsq1    = (double*)carve(256 * 8);
    double* dsum2   = (double*)carve(128 * 8);
    double* dsq2    = (double*)carve(128 * 8);
    float* a1  = (float*)carve(256 * 4);
    float* b1c = (float*)carve(256 * 4);
    float* a2  = (float*)carve(128 * 4);
    float* b2c = (float*)carve(128 * 4);

    (void)hipMemsetAsync(y1t, 0, (size_t)ZV * 256 * 4, stream);
    (void)hipMemsetAsync(dsum1, 0, (256 + 256 + 128 + 128) * 8, stream);

    tr_w1<<<512, 256, 0, stream>>>(w1, w1t);
    tr_w2b<<<128, 256, 0, stream>>>(w2, w2h, w2l);
    nn_kernel<<<2 * NP, 64, 0, stream>>>(iimg, ipts, nnImg, nnPts);
    fused_kernel<<<2 * NP, 128, 0, stream>>>(img, pts, lw, lbv, iimg, ipts, nnImg, nnPts,
                                             fusedImg, fusedPts);
    conv1_kernel<<<500, 256, 0, stream>>>(img, pts, fusedImg, fusedPts, iimg, ipts, w1t, y1t);
    stats1_kernel<<<576, 256, 0, stream>>>(y1t, dsum1, dsq1);
    fin1_kernel<<<1, 256, 0, stream>>>(dsum1, dsq1, g1, b1, a1, b1c);
    conv2_kernel<<<1152, 256, 0, stream>>>(y1t, w2h, w2l, a1, b1c, out);
    stats2_kernel<<<512, 256, 0, stream>>>(out, dsum2, dsq2);
    fin2_kernel<<<1, 128, 0, stream>>>(dsum2, dsq2, g2, b2, a2, b2c);
    final_kernel<<<18432, 256, 0, stream>>>(out, a2, b2c);
}

// Round 14
// 2520.761 us; speedup vs baseline: 2.0369x; 2.0369x over previous
//
#include <hip/hip_runtime.h>

#define ZV 147456   // 96*96*16
#define NP 2000
#define CC 128

typedef __attribute__((ext_vector_type(8))) __bf16 bf16x8;
typedef __attribute__((ext_vector_type(4))) float f32x4;

__device__ __forceinline__ int zof(int h, int w, int l) { return (h * 96 + w) * 16 + l; }

// ---------------- NN search (both directions) ----------------
__global__ void nn_kernel(const int* __restrict__ inds_img, const int* __restrict__ inds_pts,
                          int* __restrict__ nn_img, int* __restrict__ nn_pts) {
    int b = blockIdx.x;                 // 0..3999
    int q = (b < NP) ? b : b - NP;
    const int* qi = (b < NP) ? inds_pts : inds_img;
    const int* ki = (b < NP) ? inds_img : inds_pts;
    int qh = qi[q * 4 + 1], qw = qi[q * 4 + 2], ql = qi[q * 4 + 3];
    unsigned long long best = ~0ull;
    for (int k = threadIdx.x; k < NP; k += 64) {
        int dh = qh - ki[k * 4 + 1];
        int dw = qw - ki[k * 4 + 2];
        int dl = ql - ki[k * 4 + 3];
        unsigned long long d2 = (unsigned long long)(dh * dh + dw * dw + dl * dl);
        unsigned long long pack = (d2 << 32) | (unsigned)k;
        best = (pack < best) ? pack : best;
    }
    #pragma unroll
    for (int off = 32; off; off >>= 1) {
        unsigned long long o = __shfl_down(best, off, 64);
        best = (o < best) ? o : best;
    }
    if (threadIdx.x == 0) {
        int idx = (int)(best & 0xffffffffu);
        long long d2 = (long long)(best >> 32);
        int* dst = (b < NP) ? nn_img : nn_pts;
        // val < 13.3  <=>  d2 < 176.89  <=> d2 <= 176 (d2 integer)
        dst[q] = (d2 <= 176) ? idx : -1;
    }
}

// ---------------- gather + linear + elementwise (fused_img / fused_pts values) ----------------
__global__ void fused_kernel(const float* __restrict__ img, const float* __restrict__ pts,
                             const float* __restrict__ lin_w, const float* __restrict__ lin_b,
                             const int* __restrict__ inds_img, const int* __restrict__ inds_pts,
                             const int* __restrict__ nn_img, const int* __restrict__ nn_pts,
                             float* __restrict__ fusedImg, float* __restrict__ fusedPts) {
    __shared__ float f[CC];
    int b = blockIdx.x;   // 0..3999
    int t = threadIdx.x;  // 128
    int p, zsrc, zdst;
    const float* src;
    const float* selsrc;
    float* outp;
    if (b < NP) {
        p = b;
        int idx = nn_img[p]; if (idx < 0) idx += NP;     // jnp negative-index wrap
        const int* gr = inds_img + idx * 4;
        zsrc = zof(gr[1], gr[2], gr[3]);
        const int* pr = inds_pts + p * 4;
        zdst = zof(pr[1], pr[2], pr[3]);
        src = img; selsrc = pts; outp = fusedImg;
    } else {
        p = b - NP;
        int idx = nn_pts[p]; if (idx < 0) idx += NP;
        const int* gr = inds_pts + idx * 4;
        zsrc = zof(gr[1], gr[2], gr[3]);
        const int* pr = inds_img + p * 4;
        zdst = zof(pr[1], pr[2], pr[3]);
        src = pts; selsrc = img; outp = fusedPts;
    }
    f[t] = src[(size_t)t * ZV + zsrc];
    __syncthreads();
    float acc = lin_b[t];
    #pragma unroll 8
    for (int ci = 0; ci < CC; ci++) acc += f[ci] * lin_w[t * CC + ci];
    acc = fmaxf(acc, 0.f) * selsrc[(size_t)t * ZV + zdst];
    outp[p * CC + t] = acc;
}

// ---------------- weight transposes ----------------
// w1t[tap][i][o]  (tap=a*9+b*3+c, i=0..511, o=0..255)
__global__ void tr_w1(const float* __restrict__ w1, float* __restrict__ w1t) {
    int idx = blockIdx.x * 256 + threadIdx.x;   // 512*256 threads
    int o = idx & 255, i = idx >> 8;
    const float* s = w1 + ((size_t)o * 512 + i) * 27;
    #pragma unroll
    for (int tap = 0; tap < 27; tap++) w1t[((size_t)tap * 512 + i) * 256 + o] = s[tap];
}
// w2 split-precision bf16: w2h/w2l [tap][co][ci]
__global__ void tr_w2b(const float* __restrict__ w2,
                       __bf16* __restrict__ w2h, __bf16* __restrict__ w2l) {
    int idx = blockIdx.x * 256 + threadIdx.x;   // 128 blocks * 256 = 32768 = co*ci
    int ci = idx & 255, co = idx >> 8;
    const float* s = w2 + ((size_t)co * 256 + ci) * 27;
    #pragma unroll
    for (int tap = 0; tap < 27; tap++) {
        float v = s[tap];
        __bf16 hb = (__bf16)v;
        float lo = v - (float)hb;
        w2h[((size_t)tap * 128 + co) * 256 + ci] = hb;
        w2l[((size_t)tap * 128 + co) * 256 + ci] = (__bf16)lo;
    }
}

// ---------------- conv1: sparse scatter-GEMM, atomics into y1t[z][co] ----------------
__global__ __launch_bounds__(256) void conv1_kernel(
        const float* __restrict__ img, const float* __restrict__ pts,
        const float* __restrict__ fusedImg, const float* __restrict__ fusedPts,
        const int* __restrict__ inds_img, const int* __restrict__ inds_pts,
        const float* __restrict__ w1t, float* __restrict__ y1t) {
    __shared__ float VA[128][8];
    __shared__ float VB[128][8];
    __shared__ int sh[8], sw[8], sl[8];
    int wg = blockIdx.x;        // 0..499
    int s = wg / 250;           // 0: img coords (blocks 0 & 3), 1: pts coords (blocks 1 & 2)
    int chunk = wg % 250;
    int t = threadIdx.x;        // 256 = co
    const int* coords = s ? inds_pts : inds_img;
    int blA = s ? 1 : 0;
    int blB = s ? 2 : 3;
    const float* dense = s ? pts : img;
    const float* fused = s ? fusedImg : fusedPts;
    if (t < 8) {
        const int* r = coords + (chunk * 8 + t) * 4;
        sh[t] = r[1]; sw[t] = r[2]; sl[t] = r[3];
    }
    __syncthreads();
    for (int e = t; e < 1024; e += 256) {
        int ci = e >> 3, j = e & 7;
        int z = zof(sh[j], sw[j], sl[j]);
        VA[ci][j] = dense[(size_t)ci * ZV + z];
        VB[ci][j] = fused[(chunk * 8 + j) * 128 + ci];
    }
    __syncthreads();
    int co = t;
    for (int tap = 0; tap < 27; tap++) {
        int a = tap / 9, bq = (tap / 3) % 3, c = tap % 3;
        float acc[8] = {0, 0, 0, 0, 0, 0, 0, 0};
        const float* wA = w1t + ((size_t)tap * 512 + blA * 128) * 256 + co;
        const float* wB = w1t + ((size_t)tap * 512 + blB * 128) * 256 + co;
        #pragma unroll 4
        for (int ci = 0; ci < 128; ci++) {
            float a0 = wA[ci * 256];
            float b0 = wB[ci * 256];
            #pragma unroll
            for (int j = 0; j < 8; j++) acc[j] += a0 * VA[ci][j] + b0 * VB[ci][j];
        }
        #pragma unroll
        for (int j = 0; j < 8; j++) {
            int h2 = sh[j] + 1 - a, w2 = sw[j] + 1 - bq, l2 = sl[j] + 1 - c;
            if ((unsigned)h2 < 96u && (unsigned)w2 < 96u && (unsigned)l2 < 16u) {
                atomicAdd(&y1t[(size_t)zof(h2, w2, l2) * 256 + co], acc[j]);
            }
        }
    }
}

// ---------------- BN1 stats over y1t[z][co] ----------------
__global__ void stats1_kernel(const float* __restrict__ y1t, double* __restrict__ dsum,
                              double* __restrict__ dsq) {
    int t = threadIdx.x;            // co
    size_t z0 = (size_t)blockIdx.x * 256;   // 576 blocks
    double s = 0, q = 0;
    for (int r = 0; r < 256; r++) {
        float v = y1t[(z0 + r) * 256 + t];
        s += v;
        q += (double)v * v;
    }
    atomicAdd(&dsum[t], s);
    atomicAdd(&dsq[t], q);
}

__global__ void fin1_kernel(const double* dsum, const double* dsq, const float* g,
                            const float* b, float* a1, float* b1c) {
    int c = threadIdx.x;  // 256
    double mean = dsum[c] / (double)ZV;
    double var = dsq[c] / (double)ZV - mean * mean;
    float a = g[c] * (float)(1.0 / sqrt(var + 1e-3));
    a1[c] = a;
    b1c[c] = b[c] - (float)mean * a;
}

// ---------------- conv2: implicit-GEMM MFMA, bf16 split precision ----------------
// block tile: 2h x 8w x 8l = 128 voxels x 128 co; halo 4x10x10 = 400 pos (3.1x amp)
// -> LDS 51.2 KB. __launch_bounds__(256,2): do NOT force 3 waves/SIMD -- round 13
// showed the forced VGPR cap (84) spills frags to scratch (9.7 GB writes, 3.3x
// slower). With natural ~112 VGPR + 51.2 KB LDS, 3 blocks/CU fit on their own.
// 4 waves, each 64vox x 64co = 4x4 frags; K = 27 taps x 256 ci (chunk 32).
// x staged as bf16 hi/lo with XOR swizzle (16B-group ^= pidx&7); tap loop register
// double-buffered (even/odd sets, static indices).
__global__ __launch_bounds__(256, 2) void conv2_kernel(
        const float* __restrict__ y1t,
        const __bf16* __restrict__ w2h, const __bf16* __restrict__ w2l,
        const float* __restrict__ a1, const float* __restrict__ b1c,
        float* __restrict__ y2) {
    __shared__ __align__(16) __bf16 xh[400 * 32];
    __shared__ __align__(16) __bf16 xl[400 * 32];
    int bid = blockIdx.x;
    int wg = (bid & 7) * 144 + (bid >> 3);   // XCD swizzle (1152 = 8*144, bijective)
    int lh = wg & 1;
    int wt = (wg >> 1) % 12;
    int h0 = (wg / 24) * 2;
    int w0 = wt * 8;
    int l0 = lh * 8;
    int t = threadIdx.x;
    int lane = t & 63, wid = t >> 6;
    int wm = wid >> 1, wn = wid & 1;
    int r = lane & 15, kg = lane >> 4;
    int rhi = r >> 3, rlo = r & 7;

    f32x4 acc[4][4];
    #pragma unroll
    for (int i = 0; i < 4; i++)
        #pragma unroll
        for (int j = 0; j < 4; j++) acc[i][j] = (f32x4){0.f, 0.f, 0.f, 0.f};

    for (int ci0 = 0; ci0 < 256; ci0 += 32) {
        __syncthreads();    // protect previous chunk's reads
        for (int pp = t; pp < 400; pp += 256) {
            int lp = pp % 10;
            int wp = (pp / 10) % 10;
            int hp = pp / 100;
            int h2 = h0 + hp - 1, w2c = w0 + wp - 1, l2 = l0 + lp - 1;
            bool ok = ((unsigned)h2 < 96u) && ((unsigned)w2c < 96u) && ((unsigned)l2 < 16u);
            const float* src = y1t + ((size_t)zof(ok ? h2 : 0, ok ? w2c : 0, ok ? l2 : 0) * 256 + ci0);
            #pragma unroll
            for (int g4 = 0; g4 < 4; g4++) {
                float e[8];
                if (ok) {
                    float4 v0 = *(const float4*)(src + g4 * 8);
                    float4 v1 = *(const float4*)(src + g4 * 8 + 4);
                    e[0] = v0.x; e[1] = v0.y; e[2] = v0.z; e[3] = v0.w;
                    e[4] = v1.x; e[5] = v1.y; e[6] = v1.z; e[7] = v1.w;
                } else {
                    #pragma unroll
                    for (int q = 0; q < 8; q++) e[q] = 0.f;
                }
                bf16x8 hv, lv;
                #pragma unroll
                for (int q = 0; q < 8; q++) {
                    int ci = ci0 + g4 * 8 + q;
                    float x = ok ? fmaxf(a1[ci] * e[q] + b1c[ci], 0.f) : 0.f;
                    __bf16 xb = (__bf16)x;
                    hv[q] = xb;
                    lv[q] = (__bf16)(x - (float)xb);
                }
                int gs = (pp * 4 + g4) ^ (pp & 7);
                *(bf16x8*)(xh + (gs << 3)) = hv;
                *(bf16x8*)(xl + (gs << 3)) = lv;
            }
        }
        __syncthreads();

        // even/odd register frag sets -- all indices compile-time (rule: no runtime
        // indexing of ext_vector arrays).
        bf16x8 eAh[4], eAl[4], eBh[4], eBl[4];
        bf16x8 oAh[4], oAl[4], oBh[4], oBl[4];

        // A position: (hp = wm+ta, wp = mf*2+rhi+tb, lp = rlo+tc)
        #define LOADTAP(TP, Ah_, Al_, Bh_, Bl_) do {                                   \
            int ta_ = (TP) / 9, tb_ = ((TP) / 3) % 3, tc_ = (TP) % 3;                  \
            int pbase_ = (wm + ta_) * 100 + (rhi + tb_) * 10 + rlo + tc_;              \
            _Pragma("unroll")                                                          \
            for (int mf_ = 0; mf_ < 4; mf_++) {                                        \
                int pidx_ = pbase_ + mf_ * 20;                                         \
                int gs_ = (pidx_ * 4 + kg) ^ (pidx_ & 7);                              \
                Ah_[mf_] = *(const bf16x8*)(xh + (gs_ << 3));                          \
                Al_[mf_] = *(const bf16x8*)(xl + (gs_ << 3));                          \
            }                                                                          \
            size_t bbase_ = ((size_t)((TP) * 128 + wn * 64 + r)) * 256 + ci0 + kg * 8; \
            _Pragma("unroll")                                                          \
            for (int j_ = 0; j_ < 4; j_++) {                                           \
                Bh_[j_] = *(const bf16x8*)(w2h + bbase_ + j_ * 4096);                  \
                Bl_[j_] = *(const bf16x8*)(w2l + bbase_ + j_ * 4096);                  \
            }                                                                          \
        } while (0)

        // term-major MFMA order: same-acc updates are 16 MFMAs apart (no dep stall)
        #define MFMACLUSTER(Ah_, Al_, Bh_, Bl_) do {                                   \
            _Pragma("unroll")                                                          \
            for (int mf_ = 0; mf_ < 4; mf_++)                                          \
                _Pragma("unroll")                                                      \
                for (int j_ = 0; j_ < 4; j_++)                                         \
                    acc[mf_][j_] = __builtin_amdgcn_mfma_f32_16x16x32_bf16(            \
                        Ah_[mf_], Bh_[j_], acc[mf_][j_], 0, 0, 0);                     \
            _Pragma("unroll")                                                          \
            for (int mf_ = 0; mf_ < 4; mf_++)                                          \
                _Pragma("unroll")                                                      \
                for (int j_ = 0; j_ < 4; j_++)                                         \
                    acc[mf_][j_] = __builtin_amdgcn_mfma_f32_16x16x32_bf16(            \
                        Ah_[mf_], Bl_[j_], acc[mf_][j_], 0, 0, 0);                     \
            _Pragma("unroll")                                                          \
            for (int mf_ = 0; mf_ < 4; mf_++)                                          \
                _Pragma("unroll")                                                      \
                for (int j_ = 0; j_ < 4; j_++)                                         \
                    acc[mf_][j_] = __builtin_amdgcn_mfma_f32_16x16x32_bf16(            \
                        Al_[mf_], Bh_[j_], acc[mf_][j_], 0, 0, 0);                     \
        } while (0)

        LOADTAP(0, eAh, eAl, eBh, eBl);
        #pragma unroll 1
        for (int tap = 0; tap < 27; tap += 2) {
            if (tap + 1 < 27) LOADTAP(tap + 1, oAh, oAl, oBh, oBl);
            MFMACLUSTER(eAh, eAl, eBh, eBl);
            if (tap + 1 < 27) {
                if (tap + 2 < 27) LOADTAP(tap + 2, eAh, eAl, eBh, eBl);
                MFMACLUSTER(oAh, oAl, oBh, oBl);
            }
        }
        #undef LOADTAP
        #undef MFMACLUSTER
    }
    // epilogue: D col = lane&15 (co), row = kg*4 + j -> voxel (w = mf*2 + (kg>>1), l = (kg&1)*4 + j)
    #pragma unroll
    for (int mf = 0; mf < 4; mf++)
        #pragma unroll
        for (int j = 0; j < 4; j++) {
            int co = wn * 64 + j * 16 + r;
            int z = zof(h0 + wm, w0 + mf * 2 + (kg >> 1), l0 + (kg & 1) * 4);
            *(f32x4*)(y2 + (size_t)co * ZV + z) = acc[mf][j];
        }
}

// ---------------- BN2 stats over y2[co][z] ----------------
__global__ void stats2_kernel(const float* __restrict__ y2, double* __restrict__ dsum,
                              double* __restrict__ dsq) {
    __shared__ double sd[256];
    int t = threadIdx.x;
    int co = blockIdx.x >> 2, qu = blockIdx.x & 3;   // 512 blocks
    const float* pp = y2 + (size_t)co * ZV + qu * (ZV / 4);
    double s = 0, q = 0;
    for (int i = t; i < ZV / 4; i += 256) {
        float v = pp[i];
        s += v;
        q += (double)v * v;
    }
    sd[t] = s; __syncthreads();
    for (int o = 128; o; o >>= 1) { if (t < o) sd[t] += sd[t + o]; __syncthreads(); }
    if (t == 0) atomicAdd(&dsum[co], sd[0]);
    __syncthreads();
    sd[t] = q; __syncthreads();
    for (int o = 128; o; o >>= 1) { if (t < o) sd[t] += sd[t + o]; __syncthreads(); }
    if (t == 0) atomicAdd(&dsq[co], sd[0]);
}

__global__ void fin2_kernel(const double* dsum, const double* dsq, const float* g,
                            const float* b, float* a2, float* b2c) {
    int c = threadIdx.x;  // 128
    double mean = dsum[c] / (double)ZV;
    double var = dsq[c] / (double)ZV - mean * mean;
    float a = g[c] * (float)(1.0 / sqrt(var + 1e-3));
    a2[c] = a;
    b2c[c] = b[c] - (float)mean * a;
}

__global__ void final_kernel(float* __restrict__ y2, const float* __restrict__ a2,
                             const float* __restrict__ b2c) {
    int i4 = blockIdx.x * 256 + threadIdx.x;   // 4,718,592 float4s -> 18432 blocks
    size_t i = (size_t)i4 * 4;
    int co = (int)(i / ZV);
    float a = a2[co], bb = b2c[co];
    float4 v = *(float4*)(y2 + i);
    v.x = fmaxf(a * v.x + bb, 0.f);
    v.y = fmaxf(a * v.y + bb, 0.f);
    v.z = fmaxf(a * v.z + bb, 0.f);
    v.w = fmaxf(a * v.w + bb, 0.f);
    *(float4*)(y2 + i) = v;
}

extern "C" void kernel_launch(void* const* d_in, const int* in_sizes, int n_in,
                              void* d_out, int out_size, void* d_ws, size_t ws_size,
                              hipStream_t stream) {
    const float* img = (const float*)d_in[0];
    const float* pts = (const float*)d_in[1];
    const float* w1  = (const float*)d_in[2];
    const float* g1  = (const float*)d_in[3];
    const float* b1  = (const float*)d_in[4];
    const float* w2  = (const float*)d_in[5];
    const float* g2  = (const float*)d_in[6];
    const float* b2  = (const float*)d_in[7];
    const float* lw  = (const float*)d_in[8];
    const float* lbv = (const float*)d_in[9];
    const int* iimg  = (const int*)d_in[10];
    const int* ipts  = (const int*)d_in[11];
    float* out = (float*)d_out;

    char* p = (char*)d_ws;
    auto carve = [&](size_t bytes) {
        char* r = p;
        p += (bytes + 255) & ~(size_t)255;
        return r;
    };
    float* y1t      = (float*)carve((size_t)ZV * 256 * 4);       // 151 MB
    float* w1t      = (float*)carve((size_t)27 * 512 * 256 * 4); // 14.2 MB
    __bf16* w2h     = (__bf16*)carve((size_t)27 * 128 * 256 * 2); // 1.77 MB
    __bf16* w2l     = (__bf16*)carve((size_t)27 * 128 * 256 * 2); // 1.77 MB
    float* fusedImg = (float*)carve((size_t)NP * 128 * 4);
    float* fusedPts = (float*)carve((size_t)NP * 128 * 4);
    int*   nnImg    = (int*)carve(NP * 4);
    int*   nnPts    = (int*)carve(NP * 4);
    double* dsum1   = (double*)carve(256 * 8);
    double* dsq1    = (double*)carve(256 * 8);
    double* dsum2   = (double*)carve(128 * 8);
    double* dsq2    = (double*)carve(128 * 8);
    float* a1  = (float*)carve(256 * 4);
    float* b1c = (float*)carve(256 * 4);
    float* a2  = (float*)carve(128 * 4);
    float* b2c = (float*)carve(128 * 4);

    (void)hipMemsetAsync(y1t, 0, (size_t)ZV * 256 * 4, stream);
    (void)hipMemsetAsync(dsum1, 0, (256 + 256 + 128 + 128) * 8, stream);

    tr_w1<<<512, 256, 0, stream>>>(w1, w1t);
    tr_w2b<<<128, 256, 0, stream>>>(w2, w2h, w2l);
    nn_kernel<<<2 * NP, 64, 0, stream>>>(iimg, ipts, nnImg, nnPts);
    fused_kernel<<<2 * NP, 128, 0, stream>>>(img, pts, lw, lbv, iimg, ipts, nnImg, nnPts,
                                             fusedImg, fusedPts);
    conv1_kernel<<<500, 256, 0, stream>>>(img, pts, fusedImg, fusedPts, iimg, ipts, w1t, y1t);
    stats1_kernel<<<576, 256, 0, stream>>>(y1t, dsum1, dsq1);
    fin1_kernel<<<1, 256, 0, stream>>>(dsum1, dsq1, g1, b1, a1, b1c);
    conv2_kernel<<<1152, 256, 0, stream>>>(y1t, w2h, w2l, a1, b1c, out);
    stats2_kernel<<<512, 256, 0, stream>>>(out, dsum2, dsq2);
    fin2_kernel<<<1, 128, 0, stream>>>(dsum2, dsq2, g2, b2, a2, b2c);
    final_kernel<<<18432, 256, 0, stream>>>(out, a2, b2c);
}